// Round 1
// baseline (804.976 us; speedup 1.0000x reference)
//
#include <hip/hip_runtime.h>

// GCN graph classifier: 3x GCNConv(64->64, relu) + mean-pool + linear(64->10)
// N=100000 nodes, E=1600000 edges, 64 graphs.
//
// Strategy:
//  1. Build dst-CSR once per launch (histogram + block scan + atomic fill).
//  2. Per layer: dense GEMM h = x@W (W staged in LDS, thread-per-row,
//     acc[64] in registers), then gather-aggregate: one wave per node,
//     lane = feature channel, loop incoming edges reading h[src] rows
//     coalesced (256B/wave). No atomics in hot loops.
//  3. Mean-pool via sorted-batch binary search, tiny classifier GEMM.

#define HIDDEN 64

__global__ void hist_kernel(const int* __restrict__ dst, int* __restrict__ cnt, int E) {
    int e = blockIdx.x * blockDim.x + threadIdx.x;
    if (e < E) atomicAdd(&cnt[dst[e]], 1);
}

__global__ void dinv_kernel(const int* __restrict__ cnt, float* __restrict__ dinv, int N) {
    int n = blockIdx.x * blockDim.x + threadIdx.x;
    if (n < N) dinv[n] = 1.0f / sqrtf((float)(cnt[n] + 1));  // +1 self loop
}

__global__ __launch_bounds__(1024) void scan_chunk_sums(const int* __restrict__ cnt,
                                                        int* __restrict__ chunkSums, int N) {
    __shared__ int s[1024];
    int i = blockIdx.x * 1024 + threadIdx.x;
    s[threadIdx.x] = (i < N) ? cnt[i] : 0;
    __syncthreads();
    for (int off = 512; off > 0; off >>= 1) {
        if (threadIdx.x < off) s[threadIdx.x] += s[threadIdx.x + off];
        __syncthreads();
    }
    if (threadIdx.x == 0) chunkSums[blockIdx.x] = s[0];
}

__global__ void scan_offsets(int* __restrict__ chunkSums, int nChunks) {
    if (threadIdx.x == 0 && blockIdx.x == 0) {
        int acc = 0;
        for (int i = 0; i < nChunks; i++) { int v = chunkSums[i]; chunkSums[i] = acc; acc += v; }
    }
}

__global__ __launch_bounds__(1024) void scan_write(const int* __restrict__ cnt,
                                                   const int* __restrict__ chunkOffs,
                                                   int* __restrict__ rowptr, int N, int E) {
    __shared__ int s[1024];
    int i = blockIdx.x * 1024 + threadIdx.x;
    int v = (i < N) ? cnt[i] : 0;
    s[threadIdx.x] = v;
    __syncthreads();
    for (int off = 1; off < 1024; off <<= 1) {
        int t = (threadIdx.x >= off) ? s[threadIdx.x - off] : 0;
        __syncthreads();
        s[threadIdx.x] += t;
        __syncthreads();
    }
    int base = chunkOffs[blockIdx.x];
    if (i < N) rowptr[i] = base + s[threadIdx.x] - v;      // exclusive scan
    if (i == N - 1) rowptr[N] = base + s[threadIdx.x];     // total == E
}

__global__ void fill_kernel(const int* __restrict__ src, const int* __restrict__ dst,
                            const float* __restrict__ dinv, const int* __restrict__ rowptr,
                            int* __restrict__ cursor, int* __restrict__ col,
                            float* __restrict__ ew, int E) {
    int e = blockIdx.x * blockDim.x + threadIdx.x;
    if (e >= E) return;
    int s = src[e], d = dst[e];
    int pos = rowptr[d] + atomicAdd(&cursor[d], 1);
    col[pos] = s;
    ew[pos] = dinv[s] * dinv[d];
}

// h = X @ W  (X:[N,64] row-major, W:[64,64] row-major). Thread-per-row,
// W staged in LDS (broadcast reads -> conflict-free), acc[64] in VGPRs.
__global__ __launch_bounds__(256) void gemm64(const float* __restrict__ X,
                                              const float* __restrict__ W,
                                              float* __restrict__ H, int N) {
    __shared__ float Ws[64 * 64];
    for (int i = threadIdx.x; i < 64 * 64; i += 256) Ws[i] = W[i];
    __syncthreads();
    int row = blockIdx.x * 256 + threadIdx.x;
    if (row >= N) return;
    const float4* xr = reinterpret_cast<const float4*>(X + (size_t)row * 64);
    float acc[64];
#pragma unroll
    for (int j = 0; j < 64; j++) acc[j] = 0.f;
#pragma unroll
    for (int k4 = 0; k4 < 16; k4++) {
        float4 xv = xr[k4];
#pragma unroll
        for (int kk = 0; kk < 4; kk++) {
            float xk = (&xv.x)[kk];
            int k = k4 * 4 + kk;
#pragma unroll
            for (int j = 0; j < 64; j++) acc[j] += xk * Ws[k * 64 + j];
        }
    }
    float4* hr = reinterpret_cast<float4*>(H + (size_t)row * 64);
#pragma unroll
    for (int j4 = 0; j4 < 16; j4++)
        hr[j4] = make_float4(acc[4 * j4], acc[4 * j4 + 1], acc[4 * j4 + 2], acc[4 * j4 + 3]);
}

// out[n,:] = relu( sum_e w[e]*H[col[e],:] + dinv[n]^2 * H[n,:] + b )
// One wave (64 lanes) per node; lane = channel. 256B coalesced row gathers.
__global__ __launch_bounds__(256) void aggregate_kernel(const float* __restrict__ H,
                                                        const int* __restrict__ rowptr,
                                                        const int* __restrict__ col,
                                                        const float* __restrict__ ew,
                                                        const float* __restrict__ dinv,
                                                        const float* __restrict__ bias,
                                                        float* __restrict__ OUT, int N) {
    int node = blockIdx.x * 4 + (threadIdx.x >> 6);
    int lane = threadIdx.x & 63;
    if (node >= N) return;
    int beg = rowptr[node], end = rowptr[node + 1];
    float acc = 0.f;
    for (int e = beg; e < end; e++) {
        int s = col[e];
        float w = ew[e];
        acc += w * H[(size_t)s * 64 + lane];
    }
    float dn = dinv[node];
    acc += dn * dn * H[(size_t)node * 64 + lane];
    acc += bias[lane];
    acc = fmaxf(acc, 0.f);
    OUT[(size_t)node * 64 + lane] = acc;
}

__device__ __forceinline__ int lower_bound_dev(const int* a, int n, int key) {
    int lo = 0, hi = n;
    while (lo < hi) { int mid = (lo + hi) >> 1; if (a[mid] < key) lo = mid + 1; else hi = mid; }
    return lo;
}

// One block per graph; batch is sorted so graph g = contiguous [start,end).
__global__ __launch_bounds__(256) void pool_kernel(const float* __restrict__ H,
                                                   const int* __restrict__ batch,
                                                   float* __restrict__ emb, int N) {
    int g = blockIdx.x;
    int start = lower_bound_dev(batch, N, g);
    int end = lower_bound_dev(batch, N, g + 1);
    int lane = threadIdx.x & 63, wid = threadIdx.x >> 6;
    float acc = 0.f;
    for (int n = start + wid; n < end; n += 4) acc += H[(size_t)n * 64 + lane];
    __shared__ float red[4][64];
    red[wid][lane] = acc;
    __syncthreads();
    if (wid == 0) {
        float t = red[0][lane] + red[1][lane] + red[2][lane] + red[3][lane];
        int c = end - start;
        emb[g * 64 + lane] = t / (float)max(c, 1);
    }
}

// out[g,c] = sum_k emb[g,k]*Wc[k,c] + bc[c]   (64x10)
__global__ void classify_kernel(const float* __restrict__ emb, const float* __restrict__ Wc,
                                const float* __restrict__ bc, float* __restrict__ out) {
    int t = blockIdx.x * blockDim.x + threadIdx.x;
    if (t >= 64 * 10) return;
    int g = t / 10, c = t % 10;
    float acc = bc[c];
    for (int k = 0; k < 64; k++) acc += emb[g * 64 + k] * Wc[k * 10 + c];
    out[t] = acc;
}

extern "C" void kernel_launch(void* const* d_in, const int* in_sizes, int n_in,
                              void* d_out, int out_size, void* d_ws, size_t ws_size,
                              hipStream_t stream) {
    const float* x  = (const float*)d_in[0];
    const int* ei   = (const int*)d_in[1];
    const int* batch= (const int*)d_in[2];
    const float* W1 = (const float*)d_in[3];
    const float* b1 = (const float*)d_in[4];
    const float* W2 = (const float*)d_in[5];
    const float* b2 = (const float*)d_in[6];
    const float* W3 = (const float*)d_in[7];
    const float* b3 = (const float*)d_in[8];
    const float* Wc = (const float*)d_in[9];
    const float* bc = (const float*)d_in[10];

    int N = in_sizes[0] / HIDDEN;
    int E = in_sizes[1] / 2;
    const int* src = ei;
    const int* dst = ei + E;

    char* ws = (char*)d_ws;
    size_t off = 0;
    auto alloc = [&](size_t bytes) { void* p = ws + off; off = (off + bytes + 255) & ~(size_t)255; return p; };
    int*   cnt       = (int*)  alloc((size_t)N * 4);        // histogram, then cursor
    float* dinv      = (float*)alloc((size_t)N * 4);
    int*   rowptr    = (int*)  alloc((size_t)(N + 1) * 4);
    int*   chunkSums = (int*)  alloc(1024);
    int*   col       = (int*)  alloc((size_t)E * 4);
    float* ew        = (float*)alloc((size_t)E * 4);
    float* h0        = (float*)alloc((size_t)N * HIDDEN * 4);
    float* h1        = (float*)alloc((size_t)N * HIDDEN * 4);
    float* emb       = (float*)alloc(64 * 64 * 4);

    // ---- CSR build ----
    hipMemsetAsync(cnt, 0, (size_t)N * 4, stream);
    hist_kernel<<<(E + 255) / 256, 256, 0, stream>>>(dst, cnt, E);
    dinv_kernel<<<(N + 255) / 256, 256, 0, stream>>>(cnt, dinv, N);
    int nChunks = (N + 1023) / 1024;
    scan_chunk_sums<<<nChunks, 1024, 0, stream>>>(cnt, chunkSums, N);
    scan_offsets<<<1, 64, 0, stream>>>(chunkSums, nChunks);
    scan_write<<<nChunks, 1024, 0, stream>>>(cnt, chunkSums, rowptr, N, E);
    hipMemsetAsync(cnt, 0, (size_t)N * 4, stream);
    fill_kernel<<<(E + 255) / 256, 256, 0, stream>>>(src, dst, dinv, rowptr, cnt, col, ew, E);

    // ---- 3 GCN layers ----
    int gGemm = (N + 255) / 256;
    int gAgg  = (N + 3) / 4;
    gemm64<<<gGemm, 256, 0, stream>>>(x, W1, h0, N);
    aggregate_kernel<<<gAgg, 256, 0, stream>>>(h0, rowptr, col, ew, dinv, b1, h1, N);
    gemm64<<<gGemm, 256, 0, stream>>>(h1, W2, h0, N);
    aggregate_kernel<<<gAgg, 256, 0, stream>>>(h0, rowptr, col, ew, dinv, b2, h1, N);
    gemm64<<<gGemm, 256, 0, stream>>>(h1, W3, h0, N);
    aggregate_kernel<<<gAgg, 256, 0, stream>>>(h0, rowptr, col, ew, dinv, b3, h1, N);

    // ---- pool + classify ----
    pool_kernel<<<64, 256, 0, stream>>>(h1, batch, emb, N);
    classify_kernel<<<1, 640, 0, stream>>>(emb, Wc, bc, (float*)d_out);
}

// Round 2
// 547.491 us; speedup vs baseline: 1.4703x; 1.4703x over previous
//
#include <hip/hip_runtime.h>

// GCN graph classifier: 3x GCNConv(64->64, relu) + mean-pool + linear(64->10)
// N=100000 nodes, E=1600000 edges, 64 graphs.
//
// R1 -> R2: aggregate edge loop unrolled 4x (4 independent gathers in
// flight per wave; was a serial dependent chain -> VALUBusy 16%/HBM 19%,
// latency-bound at 151us). gemm64 accumulators vectorized to float4 so
// Ws reads become ds_read_b128.

#define HIDDEN 64

__global__ void hist_kernel(const int* __restrict__ dst, int* __restrict__ cnt, int E) {
    int e4 = blockIdx.x * blockDim.x + threadIdx.x;
    if (e4 * 4 + 3 < E) {
        int4 d = reinterpret_cast<const int4*>(dst)[e4];
        atomicAdd(&cnt[d.x], 1);
        atomicAdd(&cnt[d.y], 1);
        atomicAdd(&cnt[d.z], 1);
        atomicAdd(&cnt[d.w], 1);
    } else {
        for (int e = e4 * 4; e < E; e++) atomicAdd(&cnt[dst[e]], 1);
    }
}

__global__ void dinv_kernel(const int* __restrict__ cnt, float* __restrict__ dinv, int N) {
    int n = blockIdx.x * blockDim.x + threadIdx.x;
    if (n < N) dinv[n] = 1.0f / sqrtf((float)(cnt[n] + 1));  // +1 self loop
}

__global__ __launch_bounds__(1024) void scan_chunk_sums(const int* __restrict__ cnt,
                                                        int* __restrict__ chunkSums, int N) {
    __shared__ int s[1024];
    int i = blockIdx.x * 1024 + threadIdx.x;
    s[threadIdx.x] = (i < N) ? cnt[i] : 0;
    __syncthreads();
    for (int off = 512; off > 0; off >>= 1) {
        if (threadIdx.x < off) s[threadIdx.x] += s[threadIdx.x + off];
        __syncthreads();
    }
    if (threadIdx.x == 0) chunkSums[blockIdx.x] = s[0];
}

__global__ void scan_offsets(int* __restrict__ chunkSums, int nChunks) {
    if (threadIdx.x == 0 && blockIdx.x == 0) {
        int acc = 0;
        for (int i = 0; i < nChunks; i++) { int v = chunkSums[i]; chunkSums[i] = acc; acc += v; }
    }
}

__global__ __launch_bounds__(1024) void scan_write(const int* __restrict__ cnt,
                                                   const int* __restrict__ chunkOffs,
                                                   int* __restrict__ rowptr, int N, int E) {
    __shared__ int s[1024];
    int i = blockIdx.x * 1024 + threadIdx.x;
    int v = (i < N) ? cnt[i] : 0;
    s[threadIdx.x] = v;
    __syncthreads();
    for (int off = 1; off < 1024; off <<= 1) {
        int t = (threadIdx.x >= off) ? s[threadIdx.x - off] : 0;
        __syncthreads();
        s[threadIdx.x] += t;
        __syncthreads();
    }
    int base = chunkOffs[blockIdx.x];
    if (i < N) rowptr[i] = base + s[threadIdx.x] - v;      // exclusive scan
    if (i == N - 1) rowptr[N] = base + s[threadIdx.x];     // total == E
}

__global__ void fill_kernel(const int* __restrict__ src, const int* __restrict__ dst,
                            const float* __restrict__ dinv, const int* __restrict__ rowptr,
                            int* __restrict__ cursor, int* __restrict__ col,
                            float* __restrict__ ew, int E) {
    int e = blockIdx.x * blockDim.x + threadIdx.x;
    if (e >= E) return;
    int s = src[e], d = dst[e];
    int pos = rowptr[d] + atomicAdd(&cursor[d], 1);
    col[pos] = s;
    ew[pos] = dinv[s] * dinv[d];
}

// h = X @ W  (X:[N,64] row-major, W:[64,64] row-major). Thread-per-row,
// W staged in LDS; float4 accumulators -> ds_read_b128 on Ws.
__global__ __launch_bounds__(256) void gemm64(const float* __restrict__ X,
                                              const float* __restrict__ W,
                                              float* __restrict__ H, int N) {
    __shared__ float Ws[64 * 64];
    for (int i = threadIdx.x; i < 64 * 64; i += 256) Ws[i] = W[i];
    __syncthreads();
    int row = blockIdx.x * 256 + threadIdx.x;
    if (row >= N) return;
    const float4* xr = reinterpret_cast<const float4*>(X + (size_t)row * 64);
    const float4* Ws4 = reinterpret_cast<const float4*>(Ws);
    float4 acc[16];
#pragma unroll
    for (int j = 0; j < 16; j++) acc[j] = make_float4(0.f, 0.f, 0.f, 0.f);
#pragma unroll
    for (int k4 = 0; k4 < 16; k4++) {
        float4 xv = xr[k4];
#pragma unroll
        for (int kk = 0; kk < 4; kk++) {
            float xk = (&xv.x)[kk];
            int k = k4 * 4 + kk;
#pragma unroll
            for (int j = 0; j < 16; j++) {
                float4 w = Ws4[k * 16 + j];
                acc[j].x += xk * w.x;
                acc[j].y += xk * w.y;
                acc[j].z += xk * w.z;
                acc[j].w += xk * w.w;
            }
        }
    }
    float4* hr = reinterpret_cast<float4*>(H + (size_t)row * 64);
#pragma unroll
    for (int j = 0; j < 16; j++) hr[j] = acc[j];
}

// out[n,:] = relu( sum_e w[e]*H[col[e],:] + dinv[n]^2 * H[n,:] + b )
// One wave per node; lane = channel. Edge loop unrolled 4x: 4 independent
// row gathers in flight per wave (latency hiding), 4 accumulators.
__global__ __launch_bounds__(256) void aggregate_kernel(const float* __restrict__ H,
                                                        const int* __restrict__ rowptr,
                                                        const int* __restrict__ col,
                                                        const float* __restrict__ ew,
                                                        const float* __restrict__ dinv,
                                                        const float* __restrict__ bias,
                                                        float* __restrict__ OUT, int N) {
    int node = blockIdx.x * 4 + (threadIdx.x >> 6);
    int lane = threadIdx.x & 63;
    if (node >= N) return;
    int beg = __builtin_amdgcn_readfirstlane(rowptr[node]);
    int end = __builtin_amdgcn_readfirstlane(rowptr[node + 1]);
    float a0 = 0.f, a1 = 0.f, a2 = 0.f, a3 = 0.f;
    int e = beg;
    for (; e + 4 <= end; e += 4) {
        int s0 = col[e], s1 = col[e + 1], s2 = col[e + 2], s3 = col[e + 3];
        float w0 = ew[e], w1 = ew[e + 1], w2 = ew[e + 2], w3 = ew[e + 3];
        float v0 = H[(size_t)s0 * 64 + lane];
        float v1 = H[(size_t)s1 * 64 + lane];
        float v2 = H[(size_t)s2 * 64 + lane];
        float v3 = H[(size_t)s3 * 64 + lane];
        a0 += w0 * v0; a1 += w1 * v1; a2 += w2 * v2; a3 += w3 * v3;
    }
    for (; e < end; e++) a0 += ew[e] * H[(size_t)col[e] * 64 + lane];
    float acc = (a0 + a1) + (a2 + a3);
    float dn = dinv[node];
    acc += dn * dn * H[(size_t)node * 64 + lane];
    acc += bias[lane];
    acc = fmaxf(acc, 0.f);
    OUT[(size_t)node * 64 + lane] = acc;
}

__device__ __forceinline__ int lower_bound_dev(const int* a, int n, int key) {
    int lo = 0, hi = n;
    while (lo < hi) { int mid = (lo + hi) >> 1; if (a[mid] < key) lo = mid + 1; else hi = mid; }
    return lo;
}

// One block per graph; batch is sorted so graph g = contiguous [start,end).
__global__ __launch_bounds__(256) void pool_kernel(const float* __restrict__ H,
                                                   const int* __restrict__ batch,
                                                   float* __restrict__ emb, int N) {
    int g = blockIdx.x;
    int start = lower_bound_dev(batch, N, g);
    int end = lower_bound_dev(batch, N, g + 1);
    int lane = threadIdx.x & 63, wid = threadIdx.x >> 6;
    float acc = 0.f;
    for (int n = start + wid; n < end; n += 4) acc += H[(size_t)n * 64 + lane];
    __shared__ float red[4][64];
    red[wid][lane] = acc;
    __syncthreads();
    if (wid == 0) {
        float t = red[0][lane] + red[1][lane] + red[2][lane] + red[3][lane];
        int c = end - start;
        emb[g * 64 + lane] = t / (float)max(c, 1);
    }
}

// out[g,c] = sum_k emb[g,k]*Wc[k,c] + bc[c]   (64x10)
__global__ void classify_kernel(const float* __restrict__ emb, const float* __restrict__ Wc,
                                const float* __restrict__ bc, float* __restrict__ out) {
    int t = blockIdx.x * blockDim.x + threadIdx.x;
    if (t >= 64 * 10) return;
    int g = t / 10, c = t % 10;
    float acc = bc[c];
    for (int k = 0; k < 64; k++) acc += emb[g * 64 + k] * Wc[k * 10 + c];
    out[t] = acc;
}

extern "C" void kernel_launch(void* const* d_in, const int* in_sizes, int n_in,
                              void* d_out, int out_size, void* d_ws, size_t ws_size,
                              hipStream_t stream) {
    const float* x  = (const float*)d_in[0];
    const int* ei   = (const int*)d_in[1];
    const int* batch= (const int*)d_in[2];
    const float* W1 = (const float*)d_in[3];
    const float* b1 = (const float*)d_in[4];
    const float* W2 = (const float*)d_in[5];
    const float* b2 = (const float*)d_in[6];
    const float* W3 = (const float*)d_in[7];
    const float* b3 = (const float*)d_in[8];
    const float* Wc = (const float*)d_in[9];
    const float* bc = (const float*)d_in[10];

    int N = in_sizes[0] / HIDDEN;
    int E = in_sizes[1] / 2;
    const int* src = ei;
    const int* dst = ei + E;

    char* ws = (char*)d_ws;
    size_t off = 0;
    auto alloc = [&](size_t bytes) { void* p = ws + off; off = (off + bytes + 255) & ~(size_t)255; return p; };
    int*   cnt       = (int*)  alloc((size_t)N * 4);        // histogram, then cursor
    float* dinv      = (float*)alloc((size_t)N * 4);
    int*   rowptr    = (int*)  alloc((size_t)(N + 1) * 4);
    int*   chunkSums = (int*)  alloc(1024);
    int*   col       = (int*)  alloc((size_t)E * 4);
    float* ew        = (float*)alloc((size_t)E * 4);
    float* h0        = (float*)alloc((size_t)N * HIDDEN * 4);
    float* h1        = (float*)alloc((size_t)N * HIDDEN * 4);
    float* emb       = (float*)alloc(64 * 64 * 4);

    // ---- CSR build ----
    hipMemsetAsync(cnt, 0, (size_t)N * 4, stream);
    hist_kernel<<<((E + 3) / 4 + 255) / 256, 256, 0, stream>>>(dst, cnt, E);
    dinv_kernel<<<(N + 255) / 256, 256, 0, stream>>>(cnt, dinv, N);
    int nChunks = (N + 1023) / 1024;
    scan_chunk_sums<<<nChunks, 1024, 0, stream>>>(cnt, chunkSums, N);
    scan_offsets<<<1, 64, 0, stream>>>(chunkSums, nChunks);
    scan_write<<<nChunks, 1024, 0, stream>>>(cnt, chunkSums, rowptr, N, E);
    hipMemsetAsync(cnt, 0, (size_t)N * 4, stream);
    fill_kernel<<<(E + 255) / 256, 256, 0, stream>>>(src, dst, dinv, rowptr, cnt, col, ew, E);

    // ---- 3 GCN layers ----
    int gGemm = (N + 255) / 256;
    int gAgg  = (N + 3) / 4;
    gemm64<<<gGemm, 256, 0, stream>>>(x, W1, h0, N);
    aggregate_kernel<<<gAgg, 256, 0, stream>>>(h0, rowptr, col, ew, dinv, b1, h1, N);
    gemm64<<<gGemm, 256, 0, stream>>>(h1, W2, h0, N);
    aggregate_kernel<<<gAgg, 256, 0, stream>>>(h0, rowptr, col, ew, dinv, b2, h1, N);
    gemm64<<<gGemm, 256, 0, stream>>>(h1, W3, h0, N);
    aggregate_kernel<<<gAgg, 256, 0, stream>>>(h0, rowptr, col, ew, dinv, b3, h1, N);

    // ---- pool + classify ----
    pool_kernel<<<64, 256, 0, stream>>>(h1, batch, emb, N);
    classify_kernel<<<1, 640, 0, stream>>>(emb, Wc, bc, (float*)d_out);
}

// Round 3
// 504.388 us; speedup vs baseline: 1.5959x; 1.0855x over previous
//
#include <hip/hip_runtime.h>

// GCN graph classifier: 3x GCNConv(64->64, relu) + mean-pool + linear(64->10)
// N=100000 nodes, E=1600000 edges, 64 graphs.
//
// R2 -> R3:
//  - ew[] eliminated: gemm writes Hs = dinv[row]*(X@W); aggregate computes
//    relu(dinv[n]*(sum Hs[col] + Hs[n]) + b). Halves fill's scattered stores
//    (was 155MB WRITE_SIZE for 12.8MB payload) and removes ew loads per layer.
//  - pool rewritten: was 64 blocks / 2.4% occupancy / 106us serial walk.
//    Now 1 wave per 64 contiguous nodes (sorted batch -> <=2 graphs/wave),
//    local accumulate + atomicAdd flush; classifier divides by count.
//  - aggregate unrolled 8x (avg degree 16).

#define HIDDEN 64

__global__ void hist_kernel(const int* __restrict__ dst, int* __restrict__ cnt, int E) {
    int e4 = blockIdx.x * blockDim.x + threadIdx.x;
    if (e4 * 4 + 3 < E) {
        int4 d = reinterpret_cast<const int4*>(dst)[e4];
        atomicAdd(&cnt[d.x], 1);
        atomicAdd(&cnt[d.y], 1);
        atomicAdd(&cnt[d.z], 1);
        atomicAdd(&cnt[d.w], 1);
    } else {
        for (int e = e4 * 4; e < E; e++) atomicAdd(&cnt[dst[e]], 1);
    }
}

__global__ void dinv_kernel(const int* __restrict__ cnt, float* __restrict__ dinv, int N) {
    int n = blockIdx.x * blockDim.x + threadIdx.x;
    if (n < N) dinv[n] = 1.0f / sqrtf((float)(cnt[n] + 1));  // +1 self loop
}

__global__ __launch_bounds__(1024) void scan_chunk_sums(const int* __restrict__ cnt,
                                                        int* __restrict__ chunkSums, int N) {
    __shared__ int s[1024];
    int i = blockIdx.x * 1024 + threadIdx.x;
    s[threadIdx.x] = (i < N) ? cnt[i] : 0;
    __syncthreads();
    for (int off = 512; off > 0; off >>= 1) {
        if (threadIdx.x < off) s[threadIdx.x] += s[threadIdx.x + off];
        __syncthreads();
    }
    if (threadIdx.x == 0) chunkSums[blockIdx.x] = s[0];
}

__global__ void scan_offsets(int* __restrict__ chunkSums, int nChunks) {
    if (threadIdx.x == 0 && blockIdx.x == 0) {
        int acc = 0;
        for (int i = 0; i < nChunks; i++) { int v = chunkSums[i]; chunkSums[i] = acc; acc += v; }
    }
}

__global__ __launch_bounds__(1024) void scan_write(const int* __restrict__ cnt,
                                                   const int* __restrict__ chunkOffs,
                                                   int* __restrict__ rowptr, int N, int E) {
    __shared__ int s[1024];
    int i = blockIdx.x * 1024 + threadIdx.x;
    int v = (i < N) ? cnt[i] : 0;
    s[threadIdx.x] = v;
    __syncthreads();
    for (int off = 1; off < 1024; off <<= 1) {
        int t = (threadIdx.x >= off) ? s[threadIdx.x - off] : 0;
        __syncthreads();
        s[threadIdx.x] += t;
        __syncthreads();
    }
    int base = chunkOffs[blockIdx.x];
    if (i < N) rowptr[i] = base + s[threadIdx.x] - v;      // exclusive scan
    if (i == N - 1) rowptr[N] = base + s[threadIdx.x];     // total == E
}

__global__ void fill_kernel(const int* __restrict__ src, const int* __restrict__ dst,
                            const int* __restrict__ rowptr,
                            int* __restrict__ cursor, int* __restrict__ col, int E) {
    int e4 = blockIdx.x * blockDim.x + threadIdx.x;
    int base = e4 * 4;
    if (base + 3 < E) {
        int4 s = reinterpret_cast<const int4*>(src)[e4];
        int4 d = reinterpret_cast<const int4*>(dst)[e4];
        col[rowptr[d.x] + atomicAdd(&cursor[d.x], 1)] = s.x;
        col[rowptr[d.y] + atomicAdd(&cursor[d.y], 1)] = s.y;
        col[rowptr[d.z] + atomicAdd(&cursor[d.z], 1)] = s.z;
        col[rowptr[d.w] + atomicAdd(&cursor[d.w], 1)] = s.w;
    } else {
        for (int e = base; e < E; e++) {
            int s = src[e], d = dst[e];
            col[rowptr[d] + atomicAdd(&cursor[d], 1)] = s;
        }
    }
}

// Hs = dinv[row] * (X @ W)  (X:[N,64], W:[64,64] row-major, staged in LDS).
__global__ __launch_bounds__(256) void gemm64(const float* __restrict__ X,
                                              const float* __restrict__ W,
                                              const float* __restrict__ dinv,
                                              float* __restrict__ Hs, int N) {
    __shared__ float Ws[64 * 64];
    for (int i = threadIdx.x; i < 64 * 64; i += 256) Ws[i] = W[i];
    __syncthreads();
    int row = blockIdx.x * 256 + threadIdx.x;
    if (row >= N) return;
    const float4* xr = reinterpret_cast<const float4*>(X + (size_t)row * 64);
    const float4* Ws4 = reinterpret_cast<const float4*>(Ws);
    float4 acc[16];
#pragma unroll
    for (int j = 0; j < 16; j++) acc[j] = make_float4(0.f, 0.f, 0.f, 0.f);
#pragma unroll
    for (int k4 = 0; k4 < 16; k4++) {
        float4 xv = xr[k4];
#pragma unroll
        for (int kk = 0; kk < 4; kk++) {
            float xk = (&xv.x)[kk];
            int k = k4 * 4 + kk;
#pragma unroll
            for (int j = 0; j < 16; j++) {
                float4 w = Ws4[k * 16 + j];
                acc[j].x += xk * w.x;
                acc[j].y += xk * w.y;
                acc[j].z += xk * w.z;
                acc[j].w += xk * w.w;
            }
        }
    }
    float dn = dinv[row];
    float4* hr = reinterpret_cast<float4*>(Hs + (size_t)row * 64);
#pragma unroll
    for (int j = 0; j < 16; j++)
        hr[j] = make_float4(dn * acc[j].x, dn * acc[j].y, dn * acc[j].z, dn * acc[j].w);
}

// out[n,:] = relu( dinv[n] * (sum_e Hs[col[e],:] + Hs[n,:]) + b )
// One wave per node; lane = channel; 8 independent row gathers in flight.
__global__ __launch_bounds__(256) void aggregate_kernel(const float* __restrict__ Hs,
                                                        const int* __restrict__ rowptr,
                                                        const int* __restrict__ col,
                                                        const float* __restrict__ dinv,
                                                        const float* __restrict__ bias,
                                                        float* __restrict__ OUT, int N) {
    int node = blockIdx.x * 4 + (threadIdx.x >> 6);
    int lane = threadIdx.x & 63;
    if (node >= N) return;
    int beg = __builtin_amdgcn_readfirstlane(rowptr[node]);
    int end = __builtin_amdgcn_readfirstlane(rowptr[node + 1]);
    float a0 = 0.f, a1 = 0.f, a2 = 0.f, a3 = 0.f;
    float a4 = 0.f, a5 = 0.f, a6 = 0.f, a7 = 0.f;
    int e = beg;
    for (; e + 8 <= end; e += 8) {
        int s0 = col[e],     s1 = col[e + 1], s2 = col[e + 2], s3 = col[e + 3];
        int s4 = col[e + 4], s5 = col[e + 5], s6 = col[e + 6], s7 = col[e + 7];
        a0 += Hs[(size_t)s0 * 64 + lane];
        a1 += Hs[(size_t)s1 * 64 + lane];
        a2 += Hs[(size_t)s2 * 64 + lane];
        a3 += Hs[(size_t)s3 * 64 + lane];
        a4 += Hs[(size_t)s4 * 64 + lane];
        a5 += Hs[(size_t)s5 * 64 + lane];
        a6 += Hs[(size_t)s6 * 64 + lane];
        a7 += Hs[(size_t)s7 * 64 + lane];
    }
    for (; e < end; e++) a0 += Hs[(size_t)col[e] * 64 + lane];
    float acc = ((a0 + a1) + (a2 + a3)) + ((a4 + a5) + (a6 + a7));
    acc += Hs[(size_t)node * 64 + lane];                 // self loop (pre-scaled)
    acc = fmaxf(acc * dinv[node] + bias[lane], 0.f);
    OUT[(size_t)node * 64 + lane] = acc;
}

// One wave per 64 contiguous nodes; batch sorted -> few graph boundaries.
__global__ __launch_bounds__(256) void pool_partial(const float* __restrict__ H,
                                                    const int* __restrict__ batch,
                                                    float* __restrict__ sums, int N) {
    int wid = (blockIdx.x * blockDim.x + threadIdx.x) >> 6;
    int lane = threadIdx.x & 63;
    int start = wid * 64;
    if (start >= N) return;
    int end = min(start + 64, N);
    int g = batch[start];
    float acc = 0.f;
    for (int n = start; n < end; n++) {
        int bg = batch[n];
        if (bg != g) { atomicAdd(&sums[g * 64 + lane], acc); acc = 0.f; g = bg; }
        acc += H[(size_t)n * 64 + lane];
    }
    atomicAdd(&sums[g * 64 + lane], acc);
}

__device__ __forceinline__ int lower_bound_dev(const int* a, int n, int key) {
    int lo = 0, hi = n;
    while (lo < hi) { int mid = (lo + hi) >> 1; if (a[mid] < key) lo = mid + 1; else hi = mid; }
    return lo;
}

// out[g,c] = (sum_k sums[g,k]*Wc[k,c]) / cnt[g] + bc[c]
__global__ void classify_kernel(const float* __restrict__ sums, const float* __restrict__ Wc,
                                const float* __restrict__ bc, const int* __restrict__ batch,
                                float* __restrict__ out, int N) {
    int t = blockIdx.x * blockDim.x + threadIdx.x;
    if (t >= 64 * 10) return;
    int g = t / 10, c = t % 10;
    float acc = 0.f;
    for (int k = 0; k < 64; k++) acc += sums[g * 64 + k] * Wc[k * 10 + c];
    int cnt = lower_bound_dev(batch, N, g + 1) - lower_bound_dev(batch, N, g);
    out[t] = acc / (float)max(cnt, 1) + bc[c];
}

extern "C" void kernel_launch(void* const* d_in, const int* in_sizes, int n_in,
                              void* d_out, int out_size, void* d_ws, size_t ws_size,
                              hipStream_t stream) {
    const float* x  = (const float*)d_in[0];
    const int* ei   = (const int*)d_in[1];
    const int* batch= (const int*)d_in[2];
    const float* W1 = (const float*)d_in[3];
    const float* b1 = (const float*)d_in[4];
    const float* W2 = (const float*)d_in[5];
    const float* b2 = (const float*)d_in[6];
    const float* W3 = (const float*)d_in[7];
    const float* b3 = (const float*)d_in[8];
    const float* Wc = (const float*)d_in[9];
    const float* bc = (const float*)d_in[10];

    int N = in_sizes[0] / HIDDEN;
    int E = in_sizes[1] / 2;
    const int* src = ei;
    const int* dst = ei + E;

    char* ws = (char*)d_ws;
    size_t off = 0;
    auto alloc = [&](size_t bytes) { void* p = ws + off; off = (off + bytes + 255) & ~(size_t)255; return p; };
    int*   cnt       = (int*)  alloc((size_t)N * 4);        // histogram, then cursor
    float* dinv      = (float*)alloc((size_t)N * 4);
    int*   rowptr    = (int*)  alloc((size_t)(N + 1) * 4);
    int*   chunkSums = (int*)  alloc(1024);
    int*   col       = (int*)  alloc((size_t)E * 4);
    float* h0        = (float*)alloc((size_t)N * HIDDEN * 4);
    float* h1        = (float*)alloc((size_t)N * HIDDEN * 4);
    float* sums      = (float*)alloc(64 * 64 * 4);

    // ---- CSR build ----
    hipMemsetAsync(cnt, 0, (size_t)N * 4, stream);
    hist_kernel<<<((E + 3) / 4 + 255) / 256, 256, 0, stream>>>(dst, cnt, E);
    dinv_kernel<<<(N + 255) / 256, 256, 0, stream>>>(cnt, dinv, N);
    int nChunks = (N + 1023) / 1024;
    scan_chunk_sums<<<nChunks, 1024, 0, stream>>>(cnt, chunkSums, N);
    scan_offsets<<<1, 64, 0, stream>>>(chunkSums, nChunks);
    scan_write<<<nChunks, 1024, 0, stream>>>(cnt, chunkSums, rowptr, N, E);
    hipMemsetAsync(cnt, 0, (size_t)N * 4, stream);
    fill_kernel<<<((E + 3) / 4 + 255) / 256, 256, 0, stream>>>(src, dst, rowptr, cnt, col, E);

    // ---- 3 GCN layers ----
    int gGemm = (N + 255) / 256;
    int gAgg  = (N + 3) / 4;
    gemm64<<<gGemm, 256, 0, stream>>>(x, W1, dinv, h0, N);
    aggregate_kernel<<<gAgg, 256, 0, stream>>>(h0, rowptr, col, dinv, b1, h1, N);
    gemm64<<<gGemm, 256, 0, stream>>>(h1, W2, dinv, h0, N);
    aggregate_kernel<<<gAgg, 256, 0, stream>>>(h0, rowptr, col, dinv, b2, h1, N);
    gemm64<<<gGemm, 256, 0, stream>>>(h1, W3, dinv, h0, N);
    aggregate_kernel<<<gAgg, 256, 0, stream>>>(h0, rowptr, col, dinv, b3, h1, N);

    // ---- pool + classify ----
    hipMemsetAsync(sums, 0, 64 * 64 * 4, stream);
    pool_partial<<<(N + 255) / 256, 256, 0, stream>>>(h1, batch, sums, N);
    classify_kernel<<<1, 640, 0, stream>>>(sums, Wc, bc, batch, (float*)d_out, N);
}